// Round 2
// baseline (37.906 us; speedup 1.0000x reference)
//
#include <hip/hip_runtime.h>
#include <math.h>

#define B 32
#define T 262144
#define NFR 250
#define NCH 32
#define CHUNK (T / NCH)    // 8192
#define NTHR 256
#define EPT (CHUNK / NTHR) // 32

// ---------------- kernel 1: per-chunk f64 sums of f0 ----------------
__global__ __launch_bounds__(NTHR) void k_partial(const float* __restrict__ f0,
                                                  double* __restrict__ partials) {
  int row = blockIdx.y, ch = blockIdx.x, t = threadIdx.x;
  const float4* p = (const float4*)(f0 + (size_t)row * T + ch * CHUNK + t * EPT);
  double s = 0.0;
#pragma unroll
  for (int q = 0; q < EPT / 4; ++q) {
    float4 v = p[q];
    s += (double)v.x + (double)v.y + (double)v.z + (double)v.w;
  }
#pragma unroll
  for (int d = 32; d > 0; d >>= 1) s += __shfl_down(s, d);
  __shared__ double wsum[NTHR / 64];
  int lane = t & 63, wid = t >> 6;
  if (lane == 0) wsum[wid] = s;
  __syncthreads();
  if (t == 0) {
    double tot = 0.0;
#pragma unroll
    for (int w = 0; w < NTHR / 64; ++w) tot += wsum[w];
    // agent-scope publish: bypasses L1, device-coherent regardless of graph
    // node cache-maintenance behavior.
    __hip_atomic_store(&partials[row * NCH + ch], tot, __ATOMIC_RELAXED,
                       __HIP_MEMORY_SCOPE_AGENT);
  }
}

// ------- kernel 2: fused scan + envelope + FM chain (self-contained) -------
__global__ __launch_bounds__(NTHR) void k_main(const float* __restrict__ f0,
                                               const float* __restrict__ mod_index,
                                               const float* __restrict__ freq_ratio,
                                               const float* __restrict__ adsr,
                                               const double* __restrict__ partials,
                                               float* __restrict__ out) {
  int row = blockIdx.y, ch = blockIdx.x, t = threadIdx.x;
  size_t rowOff = (size_t)row * T;
  int i0 = ch * CHUNK + t * EPT;

  // load 32 f0 values, per-thread f64 sum
  const float4* fp4 = (const float4*)(f0 + rowOff + i0);
  float4 v[EPT / 4];
  double ts = 0.0;
#pragma unroll
  for (int q = 0; q < EPT / 4; ++q) {
    v[q] = fp4[q];
    ts += (double)v[q].x + (double)v[q].y + (double)v[q].z + (double)v[q].w;
  }

  // wave-level inclusive scan (shfl), then wave offsets via LDS
  int lane = t & 63, wid = t >> 6;
  double x = ts;
#pragma unroll
  for (int d = 1; d < 64; d <<= 1) {
    double n = __shfl_up(x, d);
    if (lane >= d) x += n;
  }
  __shared__ double wsum[NTHR / 64];
  __shared__ double pch[NCH];
  if (lane == 63) wsum[wid] = x;
  if (t < NCH)
    pch[t] = __hip_atomic_load(&partials[row * NCH + t], __ATOMIC_RELAXED,
                               __HIP_MEMORY_SCOPE_AGENT);
  __syncthreads();
  double wbase = 0.0;
#pragma unroll
  for (int w = 0; w < NTHR / 64; ++w) wbase += (w < wid) ? wsum[w] : 0.0;
  double cbase = 0.0;
  for (int c = 0; c < NCH; ++c) cbase += (c < ch) ? pch[c] : 0.0;
  double run = cbase + wbase + (x - ts);  // exclusive prefix for this thread

  // per-row operator constants (row-uniform -> scalar loads)
  float fr[6], mi[6];
#pragma unroll
  for (int k = 0; k < 6; ++k) {
    fr[k] = freq_ratio[row * 6 + k];
    mi[k] = 2.0f / (1.0f + expf(-mod_index[row * 6 + k]));
  }

  // envelope: this thread's 32 samples span <0.031 frames -> at most one
  // breakpoint crossing. Evaluate ADSR closed-form at 3 frames per op.
  const float step = 249.0f / (float)(T - 1);
  int i0s = (int)floorf((float)i0 * step);
  float ev0[6], ed0[6], ev1[6], ed1[6];
#pragma unroll
  for (int k = 0; k < 6; ++k) {
    const float* ap = adsr + row * 11 + k;
    float fl = ap[0], pk = ap[1];
    float a = fmaxf(ap[2], 1e-5f);
    float dd = fmaxf(ap[3], 1e-5f);
    float ss = ap[4];
    float r = fmaxf(ap[5], 1e-5f);
    float ra = 1.0f / a, rd = 1.0f / dd, rr = 1.0f / r;
    float e3[3];
#pragma unroll
    for (int j = 0; j < 3; ++j) {
      int fi = i0s + j;
      fi = (fi < NFR - 1) ? fi : NFR - 1;
      float tt = (float)fi * (1.0f / 249.0f);
      float att = fminf(fmaxf(tt * ra, 0.0f), 1.0f);
      float dec = fminf(fmaxf((tt - a) * rd, 0.0f), 1.0f);
      float rel = fminf(fmaxf((tt - (1.0f - r)) * rr, 0.0f), 1.0f);
      float env = att * (1.0f - (1.0f - ss) * dec) * (1.0f - rel);
      e3[j] = fl + (pk - fl) * env;
    }
    ev0[k] = e3[0];
    ed0[k] = e3[1] - e3[0];
    ev1[k] = e3[1];
    ed1[k] = e3[2] - e3[1];
  }

  float* op = out + rowOff + i0;
#pragma unroll
  for (int q = 0; q < EPT / 4; ++q) {
    float res[4];
#pragma unroll
    for (int j = 0; j < 4; ++j) {
      float f0v = (j == 0) ? v[q].x : (j == 1) ? v[q].y : (j == 2) ? v[q].z : v[q].w;
      run += (double)f0v;                          // inclusive prefix (f64)
      float rev = (float)run * (1.0f / 16000.0f);  // phase in revolutions
      float pos = (float)(i0 + 4 * q + j) * step;
      float fpf = floorf(pos);
      float frac = pos - fpf;
      bool hi = (fpf > (float)i0s);

      auto envv = [&](int k) {
        return hi ? fmaf(frac, ed1[k], ev1[k]) : fmaf(frac, ed0[k], ev0[k]);
      };
      auto opk = [&](int k, float mod) {
        float rv = fmaf(fr[k], rev, mod);  // revolutions: fr*omega/2pi + mod
        rv -= floorf(rv);                  // fract -> [0,1)
        return mi[k] * __builtin_amdgcn_sinf(rv) * envv(k);  // sin(2*pi*rv)
      };

      float o6 = opk(5, 0.0f);
      float o5 = opk(4, o6);
      float o4 = opk(3, o5);
      float o3 = opk(2, o4);
      float o2 = opk(1, 0.0f);
      float o1 = opk(0, o2);
      res[j] = (o3 + o1) * 0.5f;
    }
    float4 ov;
    ov.x = res[0]; ov.y = res[1]; ov.z = res[2]; ov.w = res[3];
    ((float4*)op)[q] = ov;
  }
}

extern "C" void kernel_launch(void* const* d_in, const int* in_sizes, int n_in,
                              void* d_out, int out_size, void* d_ws, size_t ws_size,
                              hipStream_t stream) {
  const float* mod_index  = (const float*)d_in[0]; // [32,6]
  const float* freq_ratio = (const float*)d_in[1]; // [32,6]
  const float* f0         = (const float*)d_in[2]; // [32,T]
  const float* adsr       = (const float*)d_in[3]; // [32,11]
  float* out = (float*)d_out;

  double* partials = (double*)d_ws;  // 32*32*8 = 8192 bytes, only ws use

  hipLaunchKernelGGL(k_partial, dim3(NCH, B), dim3(NTHR), 0, stream, f0, partials);
  hipLaunchKernelGGL(k_main, dim3(NCH, B), dim3(NTHR), 0, stream,
                     f0, mod_index, freq_ratio, adsr, partials, out);
}

// Round 3
// 34.467 us; speedup vs baseline: 1.0998x; 1.0998x over previous
//
#include <hip/hip_runtime.h>
#include <math.h>

#define B 32
#define T 262144
#define NFR 250
#define NCH 32
#define CHUNK 8192          // elements per block
#define NTHR 256
#define EPT 32              // elements per thread (contiguous ownership)

// Swizzled LDS index for logical (owner thread t, element e) in a [256][32]
// f32 tile. XOR on e's bits [4:2] keeps float4 alignment and makes BOTH the
// scattered (per-owner b128) and linear (coalesced b128) access patterns
// bank-conflict-free (each 8-lane group covers all 32 banks once).
__device__ __forceinline__ int swz(int t, int e) {
  return t * EPT + (e ^ ((t & 7) << 2));
}

// ---------------- kernel 1: per-chunk f64 sums of f0 (coalesced) ----------------
__global__ __launch_bounds__(NTHR) void k_partial(const float* __restrict__ f0,
                                                  double* __restrict__ partials) {
  int row = blockIdx.y, ch = blockIdx.x, t = threadIdx.x;
  const float4* p = (const float4*)(f0 + (size_t)row * T + ch * CHUNK);
  double s = 0.0;
#pragma unroll
  for (int i = 0; i < CHUNK / 4 / NTHR; ++i) {   // 8 coalesced float4 loads
    float4 v = p[i * NTHR + t];
    s += (double)v.x + (double)v.y + (double)v.z + (double)v.w;
  }
#pragma unroll
  for (int d = 32; d > 0; d >>= 1) s += __shfl_down(s, d);
  __shared__ double wsum[NTHR / 64];
  int lane = t & 63, wid = t >> 6;
  if (lane == 0) wsum[wid] = s;
  __syncthreads();
  if (t == 0) {
    double tot = 0.0;
#pragma unroll
    for (int w = 0; w < NTHR / 64; ++w) tot += wsum[w];
    __hip_atomic_store(&partials[row * NCH + ch], tot, __ATOMIC_RELAXED,
                       __HIP_MEMORY_SCOPE_AGENT);
  }
}

// ------- kernel 2: fused scan + envelope + FM chain, LDS-staged I/O -------
__global__ __launch_bounds__(NTHR) void k_main(const float* __restrict__ f0,
                                               const float* __restrict__ mod_index,
                                               const float* __restrict__ freq_ratio,
                                               const float* __restrict__ adsr,
                                               const double* __restrict__ partials,
                                               float* __restrict__ out) {
  __shared__ __align__(16) float tile[NTHR * EPT];  // 32 KB
  __shared__ double wsum[NTHR / 64];
  __shared__ double pch[NCH];

  int row = blockIdx.y, ch = blockIdx.x, t = threadIdx.x;
  size_t rowOff = (size_t)row * T;
  const float* fbase = f0 + rowOff + ch * CHUNK;

  // ---- coalesced global -> LDS (swizzled scatter) ----
  const float4* fp4 = (const float4*)fbase;
#pragma unroll
  for (int i = 0; i < 8; ++i) {
    float4 v = fp4[i * NTHR + t];
    int li = i * 1024 + t * 4;     // linear element index in chunk
    int tt = li >> 5;              // owner thread
    int ee = li & 31;              // element within owner (4-aligned)
    *(float4*)&tile[swz(tt, ee)] = v;
  }
  if (t < NCH)
    pch[t] = __hip_atomic_load(&partials[row * NCH + t], __ATOMIC_RELAXED,
                               __HIP_MEMORY_SCOPE_AGENT);
  __syncthreads();  // barrier 1: tile populated

  // ---- per-thread: read own 32 values, f64 sum ----
  float4 v[8];
  double ts = 0.0;
#pragma unroll
  for (int q = 0; q < 8; ++q) {
    v[q] = *(const float4*)&tile[swz(t, 4 * q)];
    ts += (double)v[q].x + (double)v[q].y + (double)v[q].z + (double)v[q].w;
  }

  // ---- wave-level inclusive scan + block combine ----
  int lane = t & 63, wid = t >> 6;
  double x = ts;
#pragma unroll
  for (int d = 1; d < 64; d <<= 1) {
    double n = __shfl_up(x, d);
    if (lane >= d) x += n;
  }
  if (lane == 63) wsum[wid] = x;
  __syncthreads();  // barrier 2: wsum ready
  double wbase = 0.0;
#pragma unroll
  for (int w = 0; w < NTHR / 64; ++w) wbase += (w < wid) ? wsum[w] : 0.0;
  double cbase = 0.0;
  for (int c = 0; c < NCH; ++c) cbase += (c < ch) ? pch[c] : 0.0;
  double run = cbase + wbase + (x - ts);  // exclusive prefix for this thread

  // ---- per-row operator constants ----
  float fr[6], mi[6];
#pragma unroll
  for (int k = 0; k < 6; ++k) {
    fr[k] = freq_ratio[row * 6 + k];
    mi[k] = 2.0f / (1.0f + expf(-mod_index[row * 6 + k]));
  }

  // ---- envelope: 3-frame local segment per op (<=1 breakpoint crossing) ----
  const float step = 249.0f / (float)(T - 1);
  int i0 = ch * CHUNK + t * EPT;
  int i0s = (int)floorf((float)i0 * step);
  float ev0[6], ed0[6], ev1[6], ed1[6];
#pragma unroll
  for (int k = 0; k < 6; ++k) {
    const float* ap = adsr + row * 11 + k;
    float fl = ap[0], pk = ap[1];
    float a = fmaxf(ap[2], 1e-5f);
    float dd = fmaxf(ap[3], 1e-5f);
    float ss = ap[4];
    float r = fmaxf(ap[5], 1e-5f);
    float ra = 1.0f / a, rd = 1.0f / dd, rr = 1.0f / r;
    float e3[3];
#pragma unroll
    for (int j = 0; j < 3; ++j) {
      int fi = i0s + j;
      fi = (fi < NFR - 1) ? fi : NFR - 1;
      float tt = (float)fi * (1.0f / 249.0f);
      float att = fminf(fmaxf(tt * ra, 0.0f), 1.0f);
      float dec = fminf(fmaxf((tt - a) * rd, 0.0f), 1.0f);
      float rel = fminf(fmaxf((tt - (1.0f - r)) * rr, 0.0f), 1.0f);
      float env = att * (1.0f - (1.0f - ss) * dec) * (1.0f - rel);
      e3[j] = fl + (pk - fl) * env;
    }
    ev0[k] = e3[0];
    ed0[k] = e3[1] - e3[0];
    ev1[k] = e3[1];
    ed1[k] = e3[2] - e3[1];
  }

  // ---- FM chain; results written back into OWN LDS slots ----
#pragma unroll
  for (int q = 0; q < 8; ++q) {
    float res[4];
#pragma unroll
    for (int j = 0; j < 4; ++j) {
      float f0v = (j == 0) ? v[q].x : (j == 1) ? v[q].y : (j == 2) ? v[q].z : v[q].w;
      run += (double)f0v;                          // inclusive prefix (f64)
      float rev = (float)run * (1.0f / 16000.0f);  // phase in revolutions
      float pos = (float)(i0 + 4 * q + j) * step;
      float fpf = floorf(pos);
      float frac = pos - fpf;
      bool hi = (fpf > (float)i0s);

      auto envv = [&](int k) {
        return hi ? fmaf(frac, ed1[k], ev1[k]) : fmaf(frac, ed0[k], ev0[k]);
      };
      auto opk = [&](int k, float mod) {
        float rv = fmaf(fr[k], rev, mod);  // fr*omega/2pi + mod, in revolutions
        rv -= floorf(rv);                  // fract -> [0,1)
        return mi[k] * __builtin_amdgcn_sinf(rv) * envv(k);  // sin(2*pi*rv)
      };

      float o6 = opk(5, 0.0f);
      float o5 = opk(4, o6);
      float o4 = opk(3, o5);
      float o3 = opk(2, o4);
      float o2 = opk(1, 0.0f);
      float o1 = opk(0, o2);
      res[j] = (o3 + o1) * 0.5f;
    }
    float4 ov;
    ov.x = res[0]; ov.y = res[1]; ov.z = res[2]; ov.w = res[3];
    *(float4*)&tile[swz(t, 4 * q)] = ov;  // own slots only
  }
  __syncthreads();  // barrier 3: all results staged

  // ---- coalesced LDS -> global store ----
  float4* ob = (float4*)(out + rowOff + ch * CHUNK);
#pragma unroll
  for (int i = 0; i < 8; ++i) {
    int li = i * 1024 + t * 4;
    int tt = li >> 5, ee = li & 31;
    ob[i * NTHR + t] = *(const float4*)&tile[swz(tt, ee)];
  }
}

extern "C" void kernel_launch(void* const* d_in, const int* in_sizes, int n_in,
                              void* d_out, int out_size, void* d_ws, size_t ws_size,
                              hipStream_t stream) {
  const float* mod_index  = (const float*)d_in[0]; // [32,6]
  const float* freq_ratio = (const float*)d_in[1]; // [32,6]
  const float* f0         = (const float*)d_in[2]; // [32,T]
  const float* adsr       = (const float*)d_in[3]; // [32,11]
  float* out = (float*)d_out;

  double* partials = (double*)d_ws;  // 32*32*8 = 8192 bytes

  hipLaunchKernelGGL(k_partial, dim3(NCH, B), dim3(NTHR), 0, stream, f0, partials);
  hipLaunchKernelGGL(k_main, dim3(NCH, B), dim3(NTHR), 0, stream,
                     f0, mod_index, freq_ratio, adsr, partials, out);
}

// Round 4
// 34.216 us; speedup vs baseline: 1.1078x; 1.0073x over previous
//
#include <hip/hip_runtime.h>
#include <math.h>

#define B 32
#define T 262144
#define NFR 250
#define NCH 64              // chunks per row
#define CHUNK 4096          // elements per block
#define NTHR 256
#define EPT 16              // elements per thread (contiguous ownership)

// Swizzled LDS index for logical (owner thread t, element e) in a [256][16]
// f32 tile. XOR on e's bits [3:2] keeps float4 alignment; both the per-owner
// b128 reads and the linear coalesced b128 accesses spread across banks.
__device__ __forceinline__ int swz(int t, int e) {
  return t * EPT + (e ^ ((t & 3) << 2));
}

// ---------------- kernel 1: per-chunk f64 sums of f0 (coalesced) ----------------
__global__ __launch_bounds__(NTHR) void k_partial(const float* __restrict__ f0,
                                                  double* __restrict__ partials) {
  int row = blockIdx.y, ch = blockIdx.x, t = threadIdx.x;
  const float4* p = (const float4*)(f0 + (size_t)row * T + ch * CHUNK);
  double s = 0.0;
#pragma unroll
  for (int i = 0; i < CHUNK / 4 / NTHR; ++i) {  // 4 coalesced float4 loads
    float4 v = p[i * NTHR + t];
    s += (double)v.x + (double)v.y + (double)v.z + (double)v.w;
  }
#pragma unroll
  for (int d = 32; d > 0; d >>= 1) s += __shfl_down(s, d);
  __shared__ double wsum[NTHR / 64];
  int lane = t & 63, wid = t >> 6;
  if (lane == 0) wsum[wid] = s;
  __syncthreads();
  if (t == 0) {
    double tot = 0.0;
#pragma unroll
    for (int w = 0; w < NTHR / 64; ++w) tot += wsum[w];
    __hip_atomic_store(&partials[row * NCH + ch], tot, __ATOMIC_RELAXED,
                       __HIP_MEMORY_SCOPE_AGENT);
  }
}

// ------- kernel 2: fused scan + envelope + FM chain, LDS-staged I/O -------
__global__ __launch_bounds__(NTHR, 8) void k_main(const float* __restrict__ f0,
                                                  const float* __restrict__ mod_index,
                                                  const float* __restrict__ freq_ratio,
                                                  const float* __restrict__ adsr,
                                                  const double* __restrict__ partials,
                                                  float* __restrict__ out) {
  __shared__ __align__(16) float tile[NTHR * EPT];  // 16 KB
  __shared__ double wsum[NTHR / 64];

  int row = blockIdx.y, ch = blockIdx.x, t = threadIdx.x;
  int lane = t & 63, wid = t >> 6;
  size_t rowOff = (size_t)row * T;

  // ---- coalesced global -> LDS (swizzled scatter) ----
  const float4* fp4 = (const float4*)(f0 + rowOff + ch * CHUNK);
#pragma unroll
  for (int i = 0; i < 4; ++i) {
    float4 v = fp4[i * NTHR + t];
    int tt = i * 64 + (t >> 2);      // owner thread of this float4
    int ee = (t & 3) * 4;            // element within owner
    *(float4*)&tile[swz(tt, ee)] = v;
  }
  __syncthreads();  // barrier 1: tile populated

  // ---- per-thread f32 sum of own 16 values (values re-read later) ----
  float fsum = 0.0f;
#pragma unroll
  for (int q = 0; q < 4; ++q) {
    float4 v = *(const float4*)&tile[swz(t, 4 * q)];
    fsum += (v.x + v.y) + (v.z + v.w);
  }
  double ts = (double)fsum;

  // ---- wave inclusive scan (f64) + cross-wave combine ----
  double x = ts;
#pragma unroll
  for (int d = 1; d < 64; d <<= 1) {
    double n = __shfl_up(x, d);
    if (lane >= d) x += n;
  }
  if (lane == 63) wsum[wid] = x;

  // chunk base: block-uniform sum of preceding chunk partials (wave-parallel)
  double pv = 0.0;
  if (lane < ch)
    pv = __hip_atomic_load(&partials[row * NCH + lane], __ATOMIC_RELAXED,
                           __HIP_MEMORY_SCOPE_AGENT);
#pragma unroll
  for (int d = 32; d > 0; d >>= 1) pv += __shfl_down(pv, d);
  double cbase = __shfl(pv, 0);

  __syncthreads();  // barrier 2: wsum ready
  double wbase = 0.0;
#pragma unroll
  for (int w = 0; w < NTHR / 64; ++w) wbase += (w < wid) ? wsum[w] : 0.0;
  // exclusive prefix (raw f0 sum) for this thread, then to f32
  float sbase = (float)(cbase + wbase + (x - ts));

  // ---- per-op constants: frs = fr/SR; envelope as 2 lines with mi folded ----
  const float step = 249.0f / (float)(T - 1);
  int i0 = ch * CHUNK + t * EPT;
  int i0s = (int)floorf((float)i0 * step);
  float pr0 = (float)i0 * step - (float)i0s;  // frame-local coord, seg0 at pr<1

  float frs[6], c0[6], s0[6], c1[6], s1[6];
#pragma unroll
  for (int k = 0; k < 6; ++k) {
    frs[k] = freq_ratio[row * 6 + k] * (1.0f / 16000.0f);
    float em = 2.0f / (1.0f + expf(-mod_index[row * 6 + k]));
    const float* ap = adsr + row * 11 + k;
    float fl = ap[0], pk = ap[1];
    float a = fmaxf(ap[2], 1e-5f);
    float dd = fmaxf(ap[3], 1e-5f);
    float ss = ap[4];
    float r = fmaxf(ap[5], 1e-5f);
    float ra = 1.0f / a, rd = 1.0f / dd, rr = 1.0f / r;
    float e3[3];
#pragma unroll
    for (int j = 0; j < 3; ++j) {
      int fi = i0s + j;
      fi = (fi < NFR - 1) ? fi : NFR - 1;
      float tt = (float)fi * (1.0f / 249.0f);
      float att = fminf(fmaxf(tt * ra, 0.0f), 1.0f);
      float dec = fminf(fmaxf((tt - a) * rd, 0.0f), 1.0f);
      float rel = fminf(fmaxf((tt - (1.0f - r)) * rr, 0.0f), 1.0f);
      float env = att * (1.0f - (1.0f - ss) * dec) * (1.0f - rel);
      e3[j] = fl + (pk - fl) * env;
    }
    c0[k] = e3[0] * em;
    s0[k] = (e3[1] - e3[0]) * em;
    s1[k] = (e3[2] - e3[1]) * em;
    c1[k] = e3[1] * em - s1[k];  // line through (1, e3[1]) with slope s1
  }

  // ---- FM chain over own 16 elements; results overwrite own LDS slots ----
  float s = sbase;
  float pr = pr0;
#pragma unroll
  for (int q = 0; q < 4; ++q) {
    float4 v = *(const float4*)&tile[swz(t, 4 * q)];
    float res[4];
#pragma unroll
    for (int j = 0; j < 4; ++j) {
      float f0v = (j == 0) ? v.x : (j == 1) ? v.y : (j == 2) ? v.z : v.w;
      s += f0v;                 // inclusive raw prefix (f32, base from f64)
      bool sel = pr >= 1.0f;

      auto opk = [&](int k, float mod) {
        float ph = fmaf(frs[k], s, mod);                  // revolutions
        float sv = __builtin_amdgcn_sinf(__builtin_amdgcn_fractf(ph));
        float e0 = fmaf(pr, s0[k], c0[k]);
        float e1 = fmaf(pr, s1[k], c1[k]);
        return sv * (sel ? e1 : e0);
      };

      float o6 = opk(5, 0.0f);
      float o2 = opk(1, 0.0f);
      float o5 = opk(4, o6);
      float o1 = opk(0, o2);
      float o4 = opk(3, o5);
      float o3 = opk(2, o4);
      res[j] = (o3 + o1) * 0.5f;
      pr += step;
    }
    float4 ov;
    ov.x = res[0]; ov.y = res[1]; ov.z = res[2]; ov.w = res[3];
    *(float4*)&tile[swz(t, 4 * q)] = ov;  // own slots only
  }
  __syncthreads();  // barrier 3: all results staged

  // ---- coalesced LDS -> global store ----
  float4* ob = (float4*)(out + rowOff + ch * CHUNK);
#pragma unroll
  for (int i = 0; i < 4; ++i) {
    int tt = i * 64 + (t >> 2);
    int ee = (t & 3) * 4;
    ob[i * NTHR + t] = *(const float4*)&tile[swz(tt, ee)];
  }
}

extern "C" void kernel_launch(void* const* d_in, const int* in_sizes, int n_in,
                              void* d_out, int out_size, void* d_ws, size_t ws_size,
                              hipStream_t stream) {
  const float* mod_index  = (const float*)d_in[0]; // [32,6]
  const float* freq_ratio = (const float*)d_in[1]; // [32,6]
  const float* f0         = (const float*)d_in[2]; // [32,T]
  const float* adsr       = (const float*)d_in[3]; // [32,11]
  float* out = (float*)d_out;

  double* partials = (double*)d_ws;  // 32*64*8 = 16384 bytes

  hipLaunchKernelGGL(k_partial, dim3(NCH, B), dim3(NTHR), 0, stream, f0, partials);
  hipLaunchKernelGGL(k_main, dim3(NCH, B), dim3(NTHR), 0, stream,
                     f0, mod_index, freq_ratio, adsr, partials, out);
}